// Round 9
// baseline (828.328 us; speedup 1.0000x reference)
//
#include <hip/hip_runtime.h>
#include <hip/hip_bf16.h>
#include <math.h>

#define BB   4
#define CCH  256
#define KK   8
#define NPIX 16384
#define TILE 64
#define NBLK 256           // tiles per batch = NPIX/TILE
#define NTILE (BB * NBLK)  // 1024 tiles
#define CGRID 512          // persistent grid: 2 tiles/block; co-residency proven below
#define TEMP_INV 1.25f     // 1/0.8
#define EPSF 1e-6f

__device__ __forceinline__ float bf_lo(unsigned int u) { return __uint_as_float(u << 16); }
__device__ __forceinline__ float bf_hi(unsigned int u) { return __uint_as_float(u & 0xffff0000u); }

struct SharedMem {
    unsigned int fb[CCH][32];   // 32 KB: bf16 feats tile, swizzled
    float cross[8][KK][66];     // 16.5 KB
    float w[KK][68];            // 2.1 KB
    float aux[8][TILE];         // 2 KB
};                              // 52.6 KiB -> 3 blocks/CU by LDS (157.9 <= 160 KiB)

// ---------------------------------------------------------------------------
// Grid barrier: monotonic counter, one arrival per block per phase.
// Reset to 0 each kernel_launch via hipMemsetAsync (graph-capturable).
// Bounded spin: residency failure -> wrong result (visible), never a hang.
// ---------------------------------------------------------------------------
__device__ __forceinline__ void gsync(unsigned int* bar, unsigned int target)
{
    __syncthreads();
    if (threadIdx.x == 0) {
        __threadfence();   // prior global writes visible device-wide
        __hip_atomic_fetch_add(bar, 1u, __ATOMIC_RELEASE, __HIP_MEMORY_SCOPE_AGENT);
        int guard = 0;
        while (__hip_atomic_load(bar, __ATOMIC_ACQUIRE, __HIP_MEMORY_SCOPE_AGENT) < target) {
            __builtin_amdgcn_s_sleep(2);
            if (++guard > 10000000) break;   // safety valve
        }
        __threadfence();
    }
    __syncthreads();
}

// ---------------------------------------------------------------------------
// One fused distance -> softmax -> accumulate tile (r6-proven body).
// ---------------------------------------------------------------------------
template<int MODE>
__device__ __forceinline__
void pass_tile(SharedMem& sm, int tile,
               const float* __restrict__ feats,
               const float* __restrict__ seed_w,
               const float* __restrict__ seed_b,
               const float* __restrict__ proto_t,
               const float* __restrict__ psq_part,
               float* __restrict__ fsq,
               float* __restrict__ part_num,
               float* __restrict__ part_den,
               float* __restrict__ logits_out,
               float* __restrict__ probs_out)
{
    const int t   = threadIdx.x;
    const int b   = tile >> 8;
    const int blk = tile & 255;
    const int n0  = blk * TILE;

    __syncthreads();   // protect LDS reuse from previous tile/phase

    // ---- phase 1: cross[k][p]; 8 waves = 8 channel-groups of 32 ----
    const int p  = t & 63;
    const int g  = t >> 6;
    const int c0 = __builtin_amdgcn_readfirstlane(g) * 32;
    const float* fcol = feats + (size_t)b * CCH * NPIX + (size_t)c0 * NPIX + n0 + p;
    const float* pt   = proto_t + (size_t)b * CCH * KK + (size_t)c0 * KK;

    float cr[KK];
    #pragma unroll
    for (int k = 0; k < KK; ++k) cr[k] = 0.f;
    float fs = 0.f;

    #pragma unroll 8
    for (int cc = 0; cc < 32; ++cc) {
        const float f = fcol[(size_t)cc * NPIX];         // coalesced 256B/wave
        if (MODE == 0) fs = fmaf(f, f, fs);
        const int c  = c0 + cc;
        const int wp = (p >> 1) ^ ((c & 15) << 1);       // swizzled word
        ((__hip_bfloat16*)sm.fb)[(c << 6) + (wp << 1) + (p & 1)] = __float2bfloat16(f);
        if (MODE == 0) {
            #pragma unroll
            for (int k = 0; k < KK; ++k)
                cr[k] = fmaf(seed_w[k * CCH + c], f, cr[k]);   // uniform -> s_load
        } else {
            const float* pr = pt + cc * KK;              // uniform -> s_load x8
            #pragma unroll
            for (int k = 0; k < KK; ++k)
                cr[k] = fmaf(pr[k], f, cr[k]);
        }
    }
    #pragma unroll
    for (int k = 0; k < KK; ++k) sm.cross[g][k][p] = cr[k];
    if (MODE == 0) sm.aux[g][p] = fs;
    __syncthreads();

    // ---- softmax over k: thread = (pixel pp, cluster k), shuffle in octet ----
    {
        const int pp = t >> 3, k = t & 7;
        float lg = 0.f;
        #pragma unroll
        for (int gg = 0; gg < 8; ++gg) lg += sm.cross[gg][k][pp];
        if (MODE == 0) {
            lg += seed_b[k];
            if (k == 0) {
                float fv = 0.f;
                #pragma unroll
                for (int gg = 0; gg < 8; ++gg) fv += sm.aux[gg][pp];
                fsq[b * NPIX + n0 + pp] = fv;
            }
        } else {
            const float fv = fsq[b * NPIX + n0 + pp];
            const float4 q0 = ((const float4*)psq_part)[(b * KK + k) * 2];
            const float4 q1 = ((const float4*)psq_part)[(b * KK + k) * 2 + 1];
            const float pk = ((q0.x + q0.y) + (q0.z + q0.w))
                           + ((q1.x + q1.y) + (q1.z + q1.w));
            lg = (2.f * lg - fv - pk) * TEMP_INV;        // -dist/TEMP
        }
        float m = lg;
        m = fmaxf(m, __shfl_xor(m, 1, 64));
        m = fmaxf(m, __shfl_xor(m, 2, 64));
        m = fmaxf(m, __shfl_xor(m, 4, 64));
        const float e = expf(lg - m);
        float ssum = e;
        ssum += __shfl_xor(ssum, 1, 64);
        ssum += __shfl_xor(ssum, 2, 64);
        ssum += __shfl_xor(ssum, 4, 64);
        const float wv = e / ssum;
        sm.w[k][pp] = wv;
        if (MODE == 2) sm.aux[k][pp] = lg;               // lg staging
    }
    __syncthreads();

    // ---- MODE 2: coalesced logits/probs writes ----
    if (MODE == 2) {
        const int k2 = t >> 6, p2 = t & 63;
        logits_out[((size_t)b * KK + k2) * NPIX + n0 + p2] = sm.aux[k2][p2];
        probs_out [((size_t)b * KK + k2) * NPIX + n0 + p2] = sm.w[k2][p2];
    }

    // ---- per-block denominator partials ----
    if (t < 256) {
        const int kk = t >> 5, ll = t & 31;
        float s = sm.w[kk][2 * ll] + sm.w[kk][2 * ll + 1];
        s += __shfl_xor(s, 16, 64);
        s += __shfl_xor(s, 8, 64);
        s += __shfl_xor(s, 4, 64);
        s += __shfl_xor(s, 2, 64);
        s += __shfl_xor(s, 1, 64);
        if (ll == 0) part_den[(b * NBLK + blk) * KK + kk] = s;
    }

    // ---- phase 2: num[k][c] from bf16 LDS tile ----
    {
        const int c = t & 255, h = t >> 8;               // 32 px per thread
        const int s2 = (c & 15) << 1;
        const uint2* row2 = (const uint2*)sm.fb[c];
        float acc[KK];
        #pragma unroll
        for (int k = 0; k < KK; ++k) acc[k] = 0.f;
        #pragma unroll
        for (int j = 0; j < 8; ++j) {
            const uint2 u = row2[((16 * h + 2 * j) ^ s2) >> 1];   // bank-optimal b64
            const float f0 = bf_lo(u.x), f1 = bf_hi(u.x);
            const float f2 = bf_lo(u.y), f3 = bf_hi(u.y);
            const int px = 32 * h + 4 * j;
            #pragma unroll
            for (int k = 0; k < KK; ++k) {
                const float4 w4 = *(const float4*)&sm.w[k][px];   // broadcast b128
                acc[k] = fmaf(f3, w4.w, fmaf(f2, w4.z,
                         fmaf(f1, w4.y, fmaf(f0, w4.x, acc[k]))));
            }
        }
        float (*acc_s)[KK][CCH] = (float (*)[KK][CCH])sm.cross;   // reuse
        #pragma unroll
        for (int k = 0; k < KK; ++k) acc_s[h][k][c] = acc[k];
        __syncthreads();
        #pragma unroll
        for (int u2 = t; u2 < KK * CCH; u2 += 512) {
            const int k = u2 >> 8, c2 = u2 & 255;
            part_num[(((size_t)b * NBLK + blk) * KK + k) * CCH + c2] =
                acc_s[0][k][c2] + acc_s[1][k][c2];
        }
    }
}

// ---------------------------------------------------------------------------
// Reduce role (r6-proven, 512 threads: 16-way j-split).
// ---------------------------------------------------------------------------
__device__ __forceinline__
void reduce_role(SharedMem& sm, int role,
                 const float* __restrict__ part_num,
                 const float* __restrict__ part_den,
                 float* __restrict__ proto_t,
                 float* __restrict__ psq_part,
                 float* __restrict__ proto_out)
{
    const int cq = role & 7;
    const int bk = role >> 3;
    const int b = bk >> 3, k = bk & 7;
    const int t = threadIdx.x;

    __syncthreads();   // LDS handoff from previous phase

    float (*red)[32] = (float (*)[32])sm.aux;            // [16][32]
    float* den_s = (float*)sm.w;                         // [4]

    float dv = (t < 256) ? part_den[(b * NBLK + t) * KK + k] : 0.f;
    dv += __shfl_xor(dv, 32, 64);
    dv += __shfl_xor(dv, 16, 64);
    dv += __shfl_xor(dv, 8, 64);
    dv += __shfl_xor(dv, 4, 64);
    dv += __shfl_xor(dv, 2, 64);
    dv += __shfl_xor(dv, 1, 64);
    if (t < 256 && (t & 63) == 0) den_s[t >> 6] = dv;

    const int jj = t >> 5, cl = t & 31;                  // 16-way j-split
    const int c = cq * 32 + cl;
    float s = 0.f;
    #pragma unroll 4
    for (int j = 0; j < 16; ++j)
        s += part_num[(((size_t)b * NBLK + jj * 16 + j) * KK + k) * CCH + c];
    red[jj][cl] = s;
    __syncthreads();

    if (t < 32) {
        const float den = den_s[0] + den_s[1] + den_s[2] + den_s[3] + EPSF;
        float pv = 0.f;
        #pragma unroll
        for (int j2 = 0; j2 < 16; ++j2) pv += red[j2][t];
        pv /= den;
        const int c2 = cq * 32 + t;
        proto_t[((size_t)b * CCH + c2) * KK + k] = pv;
        if (proto_out) proto_out[(b * KK + k) * CCH + c2] = pv;
        float q = pv * pv;                               // psq chunk partial
        q += __shfl_xor(q, 16, 64);
        q += __shfl_xor(q, 8, 64);
        q += __shfl_xor(q, 4, 64);
        q += __shfl_xor(q, 2, 64);
        q += __shfl_xor(q, 1, 64);
        if (t == 0) psq_part[(b * KK + k) * 8 + cq] = q;
    }
}

// ---------------------------------------------------------------------------
// Upsample slice: 8 float4 outputs per thread (512 blocks x 512 threads).
// ---------------------------------------------------------------------------
__device__ __forceinline__
void upsample_part(int bid, const float* __restrict__ probs, float* __restrict__ outp)
{
    const int base = bid * 512 + threadIdx.x;
    #pragma unroll
    for (int s = 0; s < 8; ++s) {
        const int gid = base + s * (CGRID * 512);        // 0..2097151
        const int jb = gid & 127;
        const int i  = (gid >> 7) & 511;
        const int bk = gid >> 16;
        const float* src = probs + (size_t)bk * NPIX;
        const float y   = i * 0.25f - 0.375f;
        const float y0f = floorf(y);
        const float fy  = y - y0f;
        const int   y0  = (int)y0f;
        const int ya = min(max(y0, 0), 127);
        const int yb = min(max(y0 + 1, 0), 127);
        const int xm = max(jb - 1, 0);
        const int xp = min(jb + 1, 127);
        const float* r0 = src + ya * 128;
        const float* r1 = src + yb * 128;
        const float wy0 = 1.f - fy;
        const float am = r0[xm] * wy0 + r1[xm] * fy;
        const float ac = r0[jb] * wy0 + r1[jb] * fy;
        const float ap = r0[xp] * wy0 + r1[xp] * fy;
        float4 o;
        o.x = 0.375f * am + 0.625f * ac;
        o.y = 0.125f * am + 0.875f * ac;
        o.z = 0.875f * ac + 0.125f * ap;
        o.w = 0.625f * ac + 0.375f * ap;
        ((float4*)outp)[gid] = o;
    }
}

// ---------------------------------------------------------------------------
// Persistent kernel, normal launch (graph-capturable).
// Co-residency: LDS 52.6KiB -> 3 blocks/CU; __launch_bounds__(512,4) caps
// VGPR<=128 -> >=2 blocks/CU; capacity >= 2*256 = 512 = grid. All blocks
// resident -> hand-rolled barrier is safe (bounded-spin valve regardless).
// ---------------------------------------------------------------------------
__global__ __launch_bounds__(512, 4)
void skm_persist(const float* __restrict__ feats,
                 const float* __restrict__ seed_w,
                 const float* __restrict__ seed_b,
                 float* __restrict__ proto_t,
                 float* __restrict__ psq_part,
                 float* __restrict__ fsq,
                 float* __restrict__ part_num,
                 float* __restrict__ part_den,
                 float* __restrict__ logits_out,
                 float* __restrict__ probs_ws,
                 float* __restrict__ probs_full,
                 float* __restrict__ proto_out,
                 unsigned int* __restrict__ bar)
{
    __shared__ SharedMem sm;
    const int bid = blockIdx.x;

    #pragma unroll 1
    for (int it = 0; it < 4; ++it) {
        if (it == 0) {
            pass_tile<0>(sm, 2 * bid,     feats, seed_w, seed_b, proto_t, psq_part,
                         fsq, part_num, part_den, nullptr, nullptr);
            pass_tile<0>(sm, 2 * bid + 1, feats, seed_w, seed_b, proto_t, psq_part,
                         fsq, part_num, part_den, nullptr, nullptr);
        } else if (it < 3) {
            pass_tile<1>(sm, 2 * bid,     feats, seed_w, seed_b, proto_t, psq_part,
                         fsq, part_num, part_den, nullptr, nullptr);
            pass_tile<1>(sm, 2 * bid + 1, feats, seed_w, seed_b, proto_t, psq_part,
                         fsq, part_num, part_den, nullptr, nullptr);
        } else {
            pass_tile<2>(sm, 2 * bid,     feats, seed_w, seed_b, proto_t, psq_part,
                         fsq, part_num, part_den, logits_out, probs_ws);
            pass_tile<2>(sm, 2 * bid + 1, feats, seed_w, seed_b, proto_t, psq_part,
                         fsq, part_num, part_den, logits_out, probs_ws);
        }
        gsync(bar, (unsigned)(2 * it + 1) * CGRID);
        if (bid < 256)
            reduce_role(sm, bid, part_num, part_den, proto_t, psq_part,
                        (it == 3) ? proto_out : nullptr);
        gsync(bar, (unsigned)(2 * it + 2) * CGRID);
    }

    upsample_part(bid, probs_ws, probs_full);
}

// ---------------------------------------------------------------------------
extern "C" void kernel_launch(void* const* d_in, const int* in_sizes, int n_in,
                              void* d_out, int out_size, void* d_ws, size_t ws_size,
                              hipStream_t stream)
{
    const float* feats  = (const float*)d_in[0];   // [4][256][16384]
    const float* seed_w = (const float*)d_in[1];   // [16][256] (first 8 rows)
    const float* seed_b = (const float*)d_in[2];   // [16]

    float* out        = (float*)d_out;
    float* probs_full = out;                        // 4*8*512*512 = 8388608
    float* proto_out  = out + 8388608;              // 4*8*256     = 8192
    float* logits_out = out + 8388608 + 8192;       // 4*8*128*128 = 524288

    float* ws       = (float*)d_ws;
    float* fsq      = ws;                           // 65536
    float* part_den = ws + 65536;                   // 8192
    float* proto_t  = part_den + 8192;              // 8192
    float* psq_part = proto_t + 8192;               // 256
    float* probs_ws = psq_part + 256;               // 524288
    float* part_num = probs_ws + 524288;            // 2097152
    unsigned int* bar = (unsigned int*)(part_num + 2097152);   // 16 words

    hipMemsetAsync(bar, 0, 64, stream);             // reset barrier (capture-legal)
    skm_persist<<<dim3(CGRID), dim3(512), 0, stream>>>(
        feats, seed_w, seed_b, proto_t, psq_part, fsq, part_num, part_den,
        logits_out, probs_ws, probs_full, proto_out, bar);
}

// Round 10
// 112.854 us; speedup vs baseline: 7.3398x; 7.3398x over previous
//
#include <hip/hip_runtime.h>
#include <hip/hip_bf16.h>
#include <math.h>

#define BB   4
#define CCH  256
#define KK   8
#define NPIX 16384
#define TILE 64
#define NBLK 256           // blocks per batch = NPIX/TILE
#define TEMP_INV 1.25f     // 1/0.8
#define EPSF 1e-6f

__device__ __forceinline__ float bf_lo(unsigned int u) { return __uint_as_float(u << 16); }
__device__ __forceinline__ float bf_hi(unsigned int u) { return __uint_as_float(u & 0xffff0000u); }
__device__ __forceinline__ unsigned short bfbits(float f) {
    __hip_bfloat16 h = __float2bfloat16(f);
    return *reinterpret_cast<unsigned short*>(&h);
}

// ---------------------------------------------------------------------------
// Pass kernel (r6-proven structure): fused distance -> softmax -> accumulate.
// MODE 0: seeds (s_load seed_w) + bias, computes f_sq, reads fp32 feats and
//         WRITES the channel-pair-packed bf16 cache feats_pk[b][c/2][n]
//         (uint = channels 2c2,2c2+1 of one pixel; 256B/wave dword stores).
// MODE 1/2: phase 1 reads feats_pk (16 uints/thread, full-width coalesced,
//         every byte used by the owning lane — fixes r4's half-width reads),
//         fills the phase-2 LDS tile with the identical bf16 bits.
// Grid: BB*NBLK = 1024 blocks x 512 threads; ~52.6 KB LDS -> 3 blocks/CU.
// bf16 tile swizzle: word w of row c stored at w ^ ((c&15)<<1).
// ---------------------------------------------------------------------------
template<int MODE>
__global__ __launch_bounds__(512, 6)
void skm_pass(const float* __restrict__ feats,
              const float* __restrict__ seed_w,
              const float* __restrict__ seed_b,
              const float* __restrict__ proto_t,   // [b][256][8]
              const float* __restrict__ psq_part,  // [b][8][8]
              float* __restrict__ fsq,
              float* __restrict__ part_num,
              float* __restrict__ part_den,
              float* __restrict__ logits_out,
              float* __restrict__ probs_out,
              unsigned int* __restrict__ feats_pk) // [b][128][16384]
{
    __shared__ unsigned int fb_s[CCH][32];   // 32 KB: bf16 feats tile, swizzled
    __shared__ float cross_s[8][KK][66];     // 16.5 KB
    __shared__ float w_s[KK][68];            // 2.1 KB (rows 16B-aligned)
    __shared__ float aux_s[8][TILE];         // 2 KB: fs partials (M0) / lg (M2)

    const int t   = threadIdx.x;
    const int bid = blockIdx.x;
    const int b   = bid >> 8;
    const int blk = bid & 255;
    const int n0  = blk * TILE;

    // ---- phase 1: cross[k][p]; 8 waves = 8 channel-groups of 32 ----
    const int p  = t & 63;                               // pixel (lane)
    const int g  = t >> 6;                               // wave = channel group
    const int c0 = __builtin_amdgcn_readfirstlane(g) * 32;
    const float* pt = proto_t + (size_t)b * CCH * KK + (size_t)c0 * KK;

    float cr[KK];
    #pragma unroll
    for (int k = 0; k < KK; ++k) cr[k] = 0.f;

    if (MODE == 0) {
        const float* fcol = feats + (size_t)b * CCH * NPIX + (size_t)c0 * NPIX + n0 + p;
        unsigned int* pkcol = feats_pk + (size_t)(b * 128 + (c0 >> 1)) * NPIX + n0 + p;
        float fs = 0.f;
        unsigned int pkbuf = 0;
        #pragma unroll 8
        for (int cc = 0; cc < 32; ++cc) {
            const float f = fcol[(size_t)cc * NPIX];     // coalesced 256B/wave
            fs = fmaf(f, f, fs);
            const int c  = c0 + cc;
            const int wp = (p >> 1) ^ ((c & 15) << 1);   // swizzled word
            const unsigned short hb = bfbits(f);
            ((unsigned short*)fb_s)[(c << 6) + (wp << 1) + (p & 1)] = hb;
            if ((cc & 1) == 0) pkbuf = hb;
            else pkcol[(size_t)(cc >> 1) * NPIX] = pkbuf | ((unsigned int)hb << 16);
            #pragma unroll
            for (int k = 0; k < KK; ++k)
                cr[k] = fmaf(seed_w[k * CCH + c], f, cr[k]);   // uniform -> s_load
        }
        aux_s[g][p] = fs;
    } else {
        const unsigned int* pkcol = feats_pk + (size_t)(b * 128 + (c0 >> 1)) * NPIX + n0 + p;
        #pragma unroll 8
        for (int j = 0; j < 16; ++j) {
            const unsigned int u = pkcol[(size_t)j * NPIX];    // coalesced 256B/wave
            const float f0 = bf_lo(u), f1 = bf_hi(u);
            const int c  = c0 + 2 * j;
            const int w0 = (p >> 1) ^ ((c & 15) << 1);
            const int w1 = (p >> 1) ^ (((c + 1) & 15) << 1);
            ((unsigned short*)fb_s)[(c << 6) + (w0 << 1) + (p & 1)] =
                (unsigned short)(u & 0xffffu);
            ((unsigned short*)fb_s)[((c + 1) << 6) + (w1 << 1) + (p & 1)] =
                (unsigned short)(u >> 16);
            const float* pr = pt + 2 * j * KK;           // uniform -> s_load
            #pragma unroll
            for (int k = 0; k < KK; ++k)
                cr[k] = fmaf(pr[k], f0, cr[k]);
            #pragma unroll
            for (int k = 0; k < KK; ++k)
                cr[k] = fmaf(pr[KK + k], f1, cr[k]);
        }
    }
    #pragma unroll
    for (int k = 0; k < KK; ++k) cross_s[g][k][p] = cr[k];
    __syncthreads();

    // ---- softmax over k: thread = (pixel pp, cluster k), shuffle in octet ----
    {
        const int pp = t >> 3, k = t & 7;
        float lg = 0.f;
        #pragma unroll
        for (int gg = 0; gg < 8; ++gg) lg += cross_s[gg][k][pp];
        if (MODE == 0) {
            lg += seed_b[k];
            if (k == 0) {
                float fv = 0.f;
                #pragma unroll
                for (int gg = 0; gg < 8; ++gg) fv += aux_s[gg][pp];
                fsq[b * NPIX + n0 + pp] = fv;
            }
        } else {
            const float fv = fsq[b * NPIX + n0 + pp];
            const float4 q0 = ((const float4*)psq_part)[(b * KK + k) * 2];
            const float4 q1 = ((const float4*)psq_part)[(b * KK + k) * 2 + 1];
            const float pk = ((q0.x + q0.y) + (q0.z + q0.w))
                           + ((q1.x + q1.y) + (q1.z + q1.w));
            lg = (2.f * lg - fv - pk) * TEMP_INV;        // -dist/TEMP
        }
        float m = lg;
        m = fmaxf(m, __shfl_xor(m, 1, 64));
        m = fmaxf(m, __shfl_xor(m, 2, 64));
        m = fmaxf(m, __shfl_xor(m, 4, 64));
        const float e = expf(lg - m);
        float ssum = e;
        ssum += __shfl_xor(ssum, 1, 64);
        ssum += __shfl_xor(ssum, 2, 64);
        ssum += __shfl_xor(ssum, 4, 64);
        const float wv = e / ssum;
        w_s[k][pp] = wv;
        if (MODE == 2) aux_s[k][pp] = lg;                // lg staging
    }
    __syncthreads();

    // ---- MODE 2: coalesced logits/probs writes ----
    if (MODE == 2) {
        const int k2 = t >> 6, p2 = t & 63;
        logits_out[((size_t)b * KK + k2) * NPIX + n0 + p2] = aux_s[k2][p2];
        probs_out [((size_t)b * KK + k2) * NPIX + n0 + p2] = w_s[k2][p2];
    }

    // ---- per-block denominator partials ----
    if (t < 256) {
        const int kk = t >> 5, ll = t & 31;
        float s = w_s[kk][2 * ll] + w_s[kk][2 * ll + 1];
        s += __shfl_xor(s, 16, 64);
        s += __shfl_xor(s, 8, 64);
        s += __shfl_xor(s, 4, 64);
        s += __shfl_xor(s, 2, 64);
        s += __shfl_xor(s, 1, 64);
        if (ll == 0) part_den[(b * NBLK + blk) * KK + kk] = s;
    }

    // ---- phase 2: num[k][c] from bf16 LDS tile ----
    {
        const int c = t & 255, h = t >> 8;               // 32 px per thread
        const int s2 = (c & 15) << 1;
        const uint2* row2 = (const uint2*)fb_s[c];
        float acc[KK];
        #pragma unroll
        for (int k = 0; k < KK; ++k) acc[k] = 0.f;
        #pragma unroll
        for (int j = 0; j < 8; ++j) {
            const uint2 u = row2[((16 * h + 2 * j) ^ s2) >> 1];   // bank-optimal b64
            const float f0 = bf_lo(u.x), f1 = bf_hi(u.x);
            const float f2 = bf_lo(u.y), f3 = bf_hi(u.y);
            const int px = 32 * h + 4 * j;
            #pragma unroll
            for (int k = 0; k < KK; ++k) {
                const float4 w4 = *(const float4*)&w_s[k][px];    // broadcast b128
                acc[k] = fmaf(f3, w4.w, fmaf(f2, w4.z,
                         fmaf(f1, w4.y, fmaf(f0, w4.x, acc[k]))));
            }
        }
        float (*acc_s)[KK][CCH] = (float (*)[KK][CCH])cross_s;   // reuse
        #pragma unroll
        for (int k = 0; k < KK; ++k) acc_s[h][k][c] = acc[k];
        __syncthreads();
        #pragma unroll
        for (int u2 = t; u2 < KK * CCH; u2 += 512) {
            const int k = u2 >> 8, c2 = u2 & 255;
            part_num[(((size_t)b * NBLK + blk) * KK + k) * CCH + c2] =
                acc_s[0][k][c2] + acc_s[1][k][c2];
        }
    }
}

// ---------------------------------------------------------------------------
// Reduce (r6-proven): 256 blocks = 32 (b,k) x 8 channel-chunks; role cq sums
// 256 j-partials (8-way j-split), divides by den, writes proto_t (+proto_out)
// AND its psq_part chunk. FINAL=true: blocks >= 256 do the bilinear x4
// upsample (part_num in ws, no alias with probs_full).
// ---------------------------------------------------------------------------
template<bool FINAL>
__global__ __launch_bounds__(256)
void skm_reduce(const float* __restrict__ part_num,
                const float* __restrict__ part_den,
                float* __restrict__ proto_t,
                float* __restrict__ psq_part,
                float* __restrict__ proto_out,
                const float* __restrict__ probs_ws,
                float* __restrict__ probs_full)
{
    const int bid = blockIdx.x;
    if (FINAL && bid >= 256) {
        // ---- upsample role: half-pixel bilinear x4, edge clamp ----
        const int gid = (bid - 256) * 256 + threadIdx.x;   // 0..2097151
        const int jb = gid & 127;
        const int i  = (gid >> 7) & 511;
        const int bk = gid >> 16;
        const float* src = probs_ws + (size_t)bk * NPIX;
        const float y   = i * 0.25f - 0.375f;
        const float y0f = floorf(y);
        const float fy  = y - y0f;
        const int   y0  = (int)y0f;
        const int ya = min(max(y0, 0), 127);
        const int yb = min(max(y0 + 1, 0), 127);
        const int xm = max(jb - 1, 0);
        const int xp = min(jb + 1, 127);
        const float* r0 = src + ya * 128;
        const float* r1 = src + yb * 128;
        const float wy0 = 1.f - fy;
        const float am = r0[xm] * wy0 + r1[xm] * fy;
        const float ac = r0[jb] * wy0 + r1[jb] * fy;
        const float ap = r0[xp] * wy0 + r1[xp] * fy;
        float4 o;
        o.x = 0.375f * am + 0.625f * ac;
        o.y = 0.125f * am + 0.875f * ac;
        o.z = 0.875f * ac + 0.125f * ap;
        o.w = 0.625f * ac + 0.375f * ap;
        ((float4*)probs_full)[gid] = o;
        return;
    }

    const int cq = bid & 7;
    const int bk = bid >> 3;             // 0..31
    const int b = bk >> 3, k = bk & 7;
    const int t = threadIdx.x;

    __shared__ float red[8][32];
    __shared__ float den_s[4];

    // denominator: 256 threads read 256 block-partials, per-wave shuffle tree
    float dv = part_den[(b * NBLK + t) * KK + k];
    dv += __shfl_xor(dv, 32, 64);
    dv += __shfl_xor(dv, 16, 64);
    dv += __shfl_xor(dv, 8, 64);
    dv += __shfl_xor(dv, 4, 64);
    dv += __shfl_xor(dv, 2, 64);
    dv += __shfl_xor(dv, 1, 64);
    if ((t & 63) == 0) den_s[t >> 6] = dv;

    // numerator: 8-way j-split over this role's 32 channels
    const int jj = t >> 5, cl = t & 31;
    const int c = cq * 32 + cl;
    float s = 0.f;
    #pragma unroll 4
    for (int j = 0; j < 32; ++j)
        s += part_num[(((size_t)b * NBLK + jj * 32 + j) * KK + k) * CCH + c];
    red[jj][cl] = s;
    __syncthreads();

    if (t < 32) {
        const float den = den_s[0] + den_s[1] + den_s[2] + den_s[3] + EPSF;
        float pv = 0.f;
        #pragma unroll
        for (int j2 = 0; j2 < 8; ++j2) pv += red[j2][t];
        pv /= den;
        const int c2 = cq * 32 + t;
        proto_t[((size_t)b * CCH + c2) * KK + k] = pv;
        if (proto_out) proto_out[(b * KK + k) * CCH + c2] = pv;
        float q = pv * pv;                               // psq chunk partial
        q += __shfl_xor(q, 16, 64);
        q += __shfl_xor(q, 8, 64);
        q += __shfl_xor(q, 4, 64);
        q += __shfl_xor(q, 2, 64);
        q += __shfl_xor(q, 1, 64);
        if (t == 0) psq_part[(b * KK + k) * 8 + cq] = q;
    }
}

// ---------------------------------------------------------------------------
extern "C" void kernel_launch(void* const* d_in, const int* in_sizes, int n_in,
                              void* d_out, int out_size, void* d_ws, size_t ws_size,
                              hipStream_t stream)
{
    const float* feats  = (const float*)d_in[0];   // [4][256][16384]
    const float* seed_w = (const float*)d_in[1];   // [16][256] (first 8 rows)
    const float* seed_b = (const float*)d_in[2];   // [16]

    float* out        = (float*)d_out;
    float* probs_full = out;                        // 4*8*512*512 = 8388608
    float* proto_out  = out + 8388608;              // 4*8*256     = 8192
    float* logits_out = out + 8388608 + 8192;       // 4*8*128*128 = 524288

    float* ws       = (float*)d_ws;
    float* fsq      = ws;                           // 65536
    float* part_den = ws + 65536;                   // 4*256*8 = 8192
    float* proto_t  = part_den + 8192;              // 8192
    float* psq_part = proto_t + 8192;               // 256
    float* probs_ws = psq_part + 256;               // 524288
    float* part_num = probs_ws + 524288;            // 2097152
    unsigned int* feats_pk = (unsigned int*)(part_num + 2097152);  // 4*128*16384 = 8388608 u32 (~44 MB total)

    const dim3 pg(BB * NBLK), pb(512);
    const dim3 rg(256), rb(256);

    // seed pass (writes packed bf16 cache) + initial proto
    skm_pass<0><<<pg, pb, 0, stream>>>(feats, seed_w, seed_b, proto_t, psq_part,
                                       fsq, part_num, part_den, nullptr, nullptr, feats_pk);
    skm_reduce<false><<<rg, rb, 0, stream>>>(part_num, part_den, proto_t, psq_part,
                                             nullptr, probs_ws, probs_full);
    // cluster iterations 1,2 (read packed cache: half the feats traffic)
    skm_pass<1><<<pg, pb, 0, stream>>>(feats, seed_w, seed_b, proto_t, psq_part,
                                       fsq, part_num, part_den, nullptr, nullptr, feats_pk);
    skm_reduce<false><<<rg, rb, 0, stream>>>(part_num, part_den, proto_t, psq_part,
                                             nullptr, probs_ws, probs_full);
    skm_pass<1><<<pg, pb, 0, stream>>>(feats, seed_w, seed_b, proto_t, psq_part,
                                       fsq, part_num, part_den, nullptr, nullptr, feats_pk);
    skm_reduce<false><<<rg, rb, 0, stream>>>(part_num, part_den, proto_t, psq_part,
                                             nullptr, probs_ws, probs_full);
    // iteration 3: emit logits_map + probs(=assign)
    skm_pass<2><<<pg, pb, 0, stream>>>(feats, seed_w, seed_b, proto_t, psq_part,
                                       fsq, part_num, part_den, logits_out, probs_ws, feats_pk);
    // final reduce (proto -> d_out) + fused bilinear x4 upsample
    skm_reduce<true><<<dim3(256 + 8192), rb, 0, stream>>>(part_num, part_den, proto_t, psq_part,
                                                          proto_out, probs_ws, probs_full);
}

// Round 11
// 97.929 us; speedup vs baseline: 8.4585x; 1.1524x over previous
//
#include <hip/hip_runtime.h>
#include <hip/hip_bf16.h>
#include <math.h>

#define BB   4
#define CCH  256
#define KK   8
#define NPIX 16384
#define TILE 64
#define NBLK 256           // blocks per batch = NPIX/TILE
#define TEMP_INV 1.25f     // 1/0.8
#define EPSF 1e-6f

__device__ __forceinline__ float bf_lo(unsigned int u) { return __uint_as_float(u << 16); }
__device__ __forceinline__ float bf_hi(unsigned int u) { return __uint_as_float(u & 0xffff0000u); }

// ---------------------------------------------------------------------------
// Pass kernel (r6-proven structure): fused distance -> softmax -> accumulate;
// feats read from global ONCE (phase 1, fp32 coalesced); phase 2 re-reads a
// bf16 LDS copy.  [r4/r10 lesson: feats is L3-resident after pass 0 -- do NOT
// try to cache it in bf16; r7/r9 lesson: no cross-block sync on this chip.]
// MODE 0: seeds (s_load seed_w) + bias, computes f_sq.
// MODE 1: cluster iteration; f_sq DROPPED from logit (softmax-invariant).
// MODE 2: iteration + emit logits/probs (keeps f_sq for the logits output).
// Grid: BB*NBLK = 1024 blocks x 512 threads; ~52.6 KB LDS -> 3 blocks/CU.
// bf16 tile swizzle: word w of row c stored at w ^ ((c&15)<<1).
// ---------------------------------------------------------------------------
template<int MODE>
__global__ __launch_bounds__(512, 6)
void skm_pass(const float* __restrict__ feats,
              const float* __restrict__ seed_w,
              const float* __restrict__ seed_b,
              const float* __restrict__ proto_t,   // [b][256][8]
              const float* __restrict__ psq_part,  // [b][8][8]
              float* __restrict__ fsq,
              float* __restrict__ part_num,
              float* __restrict__ part_den,
              float* __restrict__ logits_out,
              float* __restrict__ probs_out)
{
    __shared__ unsigned int fb_s[CCH][32];   // 32 KB: bf16 feats tile, swizzled
    __shared__ float cross_s[8][KK][66];     // 16.5 KB
    __shared__ float w_s[KK][68];            // 2.1 KB (rows 16B-aligned)
    __shared__ float aux_s[8][TILE];         // 2 KB: fs partials (M0) / lg (M2)

    const int t   = threadIdx.x;
    const int bid = blockIdx.x;
    const int b   = bid >> 8;
    const int blk = bid & 255;
    const int n0  = blk * TILE;

    // ---- phase 1: cross[k][p]; 8 waves = 8 channel-groups of 32 ----
    const int p  = t & 63;                               // pixel (lane)
    const int g  = t >> 6;                               // wave = channel group
    const int c0 = __builtin_amdgcn_readfirstlane(g) * 32;
    const float* fcol = feats + (size_t)b * CCH * NPIX + (size_t)c0 * NPIX + n0 + p;
    const float* pt   = proto_t + (size_t)b * CCH * KK + (size_t)c0 * KK;

    float cr[KK];
    #pragma unroll
    for (int k = 0; k < KK; ++k) cr[k] = 0.f;
    float fs = 0.f;

    #pragma unroll 8
    for (int cc = 0; cc < 32; ++cc) {
        const float f = fcol[(size_t)cc * NPIX];         // coalesced 256B/wave
        if (MODE == 0) fs = fmaf(f, f, fs);
        const int c  = c0 + cc;
        const int wp = (p >> 1) ^ ((c & 15) << 1);       // swizzled word
        ((__hip_bfloat16*)fb_s)[(c << 6) + (wp << 1) + (p & 1)] = __float2bfloat16(f);
        if (MODE == 0) {
            #pragma unroll
            for (int k = 0; k < KK; ++k)
                cr[k] = fmaf(seed_w[k * CCH + c], f, cr[k]);   // uniform -> s_load
        } else {
            const float* pr = pt + cc * KK;              // uniform -> s_load x8
            #pragma unroll
            for (int k = 0; k < KK; ++k)
                cr[k] = fmaf(pr[k], f, cr[k]);
        }
    }
    #pragma unroll
    for (int k = 0; k < KK; ++k) cross_s[g][k][p] = cr[k];
    if (MODE == 0) aux_s[g][p] = fs;
    __syncthreads();

    // ---- softmax over k: thread = (pixel pp, cluster k), shuffle in octet ----
    {
        const int pp = t >> 3, k = t & 7;
        float lg = 0.f;
        #pragma unroll
        for (int gg = 0; gg < 8; ++gg) lg += cross_s[gg][k][pp];
        if (MODE == 0) {
            lg += seed_b[k];
            if (k == 0) {
                float fv = 0.f;
                #pragma unroll
                for (int gg = 0; gg < 8; ++gg) fv += aux_s[gg][pp];
                fsq[b * NPIX + n0 + pp] = fv;
            }
        } else {
            const float4 q0 = ((const float4*)psq_part)[(b * KK + k) * 2];
            const float4 q1 = ((const float4*)psq_part)[(b * KK + k) * 2 + 1];
            const float pk = ((q0.x + q0.y) + (q0.z + q0.w))
                           + ((q1.x + q1.y) + (q1.z + q1.w));
            if (MODE == 2) {
                const float fv = fsq[b * NPIX + n0 + pp];
                lg = (2.f * lg - fv - pk) * TEMP_INV;    // true -dist/TEMP (output)
            } else {
                // f_sq is constant over k -> softmax-invariant: drop it.
                lg = fmaf(2.f * TEMP_INV, lg, -TEMP_INV * pk);
            }
        }
        float m = lg;
        m = fmaxf(m, __shfl_xor(m, 1, 64));
        m = fmaxf(m, __shfl_xor(m, 2, 64));
        m = fmaxf(m, __shfl_xor(m, 4, 64));
        const float e = expf(lg - m);
        float ssum = e;
        ssum += __shfl_xor(ssum, 1, 64);
        ssum += __shfl_xor(ssum, 2, 64);
        ssum += __shfl_xor(ssum, 4, 64);
        const float wv = e / ssum;
        w_s[k][pp] = wv;
        if (MODE == 2) aux_s[k][pp] = lg;                // lg staging
    }
    __syncthreads();

    // ---- MODE 2: coalesced logits/probs writes ----
    if (MODE == 2) {
        const int k2 = t >> 6, p2 = t & 63;
        logits_out[((size_t)b * KK + k2) * NPIX + n0 + p2] = aux_s[k2][p2];
        probs_out [((size_t)b * KK + k2) * NPIX + n0 + p2] = w_s[k2][p2];
    }

    // ---- per-block denominator partials ----
    if (t < 256) {
        const int kk = t >> 5, ll = t & 31;
        float s = w_s[kk][2 * ll] + w_s[kk][2 * ll + 1];
        s += __shfl_xor(s, 16, 64);
        s += __shfl_xor(s, 8, 64);
        s += __shfl_xor(s, 4, 64);
        s += __shfl_xor(s, 2, 64);
        s += __shfl_xor(s, 1, 64);
        if (ll == 0) part_den[(b * NBLK + blk) * KK + kk] = s;
    }

    // ---- phase 2: num[k][c] from bf16 LDS tile (dual even/odd FMA chains) ----
    {
        const int c = t & 255, h = t >> 8;               // 32 px per thread
        const int s2 = (c & 15) << 1;
        const uint2* row2 = (const uint2*)fb_s[c];
        float accx[KK], accy[KK];
        #pragma unroll
        for (int k = 0; k < KK; ++k) { accx[k] = 0.f; accy[k] = 0.f; }
        #pragma unroll
        for (int j = 0; j < 8; ++j) {
            const uint2 u = row2[((16 * h + 2 * j) ^ s2) >> 1];   // b64
            const float f0 = bf_lo(u.x), f1 = bf_hi(u.x);
            const float f2 = bf_lo(u.y), f3 = bf_hi(u.y);
            const int px = 32 * h + 4 * j;
            #pragma unroll
            for (int k = 0; k < KK; ++k) {
                const float4 w4 = *(const float4*)&w_s[k][px];    // broadcast b128
                accx[k] = fmaf(f2, w4.z, fmaf(f0, w4.x, accx[k]));
                accy[k] = fmaf(f3, w4.w, fmaf(f1, w4.y, accy[k]));
            }
        }
        float (*acc_s)[KK][CCH] = (float (*)[KK][CCH])cross_s;   // reuse
        #pragma unroll
        for (int k = 0; k < KK; ++k) acc_s[h][k][c] = accx[k] + accy[k];
        __syncthreads();
        #pragma unroll
        for (int u2 = t; u2 < KK * CCH; u2 += 512) {
            const int k = u2 >> 8, c2 = u2 & 255;
            part_num[(((size_t)b * NBLK + blk) * KK + k) * CCH + c2] =
                acc_s[0][k][c2] + acc_s[1][k][c2];
        }
    }
}

// ---------------------------------------------------------------------------
// Reduce (512 threads, 16-way j-split — ran correctly inside r9's persist):
// 256 blocks = 32 (b,k) x 8 channel-chunks; role cq sums 256 j-partials,
// divides by den, writes proto_t (+proto_out) AND its psq_part chunk.
// FINAL=true: blocks >= 256 do the bilinear x4 upsample (512-wide).
// ---------------------------------------------------------------------------
template<bool FINAL>
__global__ __launch_bounds__(512)
void skm_reduce(const float* __restrict__ part_num,
                const float* __restrict__ part_den,
                float* __restrict__ proto_t,
                float* __restrict__ psq_part,
                float* __restrict__ proto_out,
                const float* __restrict__ probs_ws,
                float* __restrict__ probs_full)
{
    const int bid = blockIdx.x;
    if (FINAL && bid >= 256) {
        // ---- upsample role: half-pixel bilinear x4, edge clamp ----
        const int gid = (bid - 256) * 512 + threadIdx.x;   // 0..2097151
        const int jb = gid & 127;
        const int i  = (gid >> 7) & 511;
        const int bk = gid >> 16;
        const float* src = probs_ws + (size_t)bk * NPIX;
        const float y   = i * 0.25f - 0.375f;
        const float y0f = floorf(y);
        const float fy  = y - y0f;
        const int   y0  = (int)y0f;
        const int ya = min(max(y0, 0), 127);
        const int yb = min(max(y0 + 1, 0), 127);
        const int xm = max(jb - 1, 0);
        const int xp = min(jb + 1, 127);
        const float* r0 = src + ya * 128;
        const float* r1 = src + yb * 128;
        const float wy0 = 1.f - fy;
        const float am = r0[xm] * wy0 + r1[xm] * fy;
        const float ac = r0[jb] * wy0 + r1[jb] * fy;
        const float ap = r0[xp] * wy0 + r1[xp] * fy;
        float4 o;
        o.x = 0.375f * am + 0.625f * ac;
        o.y = 0.125f * am + 0.875f * ac;
        o.z = 0.875f * ac + 0.125f * ap;
        o.w = 0.625f * ac + 0.375f * ap;
        ((float4*)probs_full)[gid] = o;
        return;
    }

    const int cq = bid & 7;
    const int bk = bid >> 3;             // 0..31
    const int b = bk >> 3, k = bk & 7;
    const int t = threadIdx.x;

    __shared__ float red[16][32];
    __shared__ float den_s[4];

    // denominator: threads 0-255 read 256 block-partials, per-wave shuffle tree
    float dv = (t < 256) ? part_den[(b * NBLK + t) * KK + k] : 0.f;
    dv += __shfl_xor(dv, 32, 64);
    dv += __shfl_xor(dv, 16, 64);
    dv += __shfl_xor(dv, 8, 64);
    dv += __shfl_xor(dv, 4, 64);
    dv += __shfl_xor(dv, 2, 64);
    dv += __shfl_xor(dv, 1, 64);
    if (t < 256 && (t & 63) == 0) den_s[t >> 6] = dv;

    // numerator: 16-way j-split over this role's 32 channels
    const int jj = t >> 5, cl = t & 31;
    const int c = cq * 32 + cl;
    float s = 0.f;
    #pragma unroll 4
    for (int j = 0; j < 16; ++j)
        s += part_num[(((size_t)b * NBLK + jj * 16 + j) * KK + k) * CCH + c];
    red[jj][cl] = s;
    __syncthreads();

    if (t < 32) {
        const float den = den_s[0] + den_s[1] + den_s[2] + den_s[3] + EPSF;
        float pv = 0.f;
        #pragma unroll
        for (int j2 = 0; j2 < 16; ++j2) pv += red[j2][t];
        pv /= den;
        const int c2 = cq * 32 + t;
        proto_t[((size_t)b * CCH + c2) * KK + k] = pv;
        if (proto_out) proto_out[(b * KK + k) * CCH + c2] = pv;
        float q = pv * pv;                               // psq chunk partial
        q += __shfl_xor(q, 16, 64);
        q += __shfl_xor(q, 8, 64);
        q += __shfl_xor(q, 4, 64);
        q += __shfl_xor(q, 2, 64);
        q += __shfl_xor(q, 1, 64);
        if (t == 0) psq_part[(b * KK + k) * 8 + cq] = q;
    }
}

// ---------------------------------------------------------------------------
extern "C" void kernel_launch(void* const* d_in, const int* in_sizes, int n_in,
                              void* d_out, int out_size, void* d_ws, size_t ws_size,
                              hipStream_t stream)
{
    const float* feats  = (const float*)d_in[0];   // [4][256][16384]
    const float* seed_w = (const float*)d_in[1];   // [16][256] (first 8 rows)
    const float* seed_b = (const float*)d_in[2];   // [16]

    float* out        = (float*)d_out;
    float* probs_full = out;                        // 4*8*512*512 = 8388608
    float* proto_out  = out + 8388608;              // 4*8*256     = 8192
    float* logits_out = out + 8388608 + 8192;       // 4*8*128*128 = 524288

    float* ws       = (float*)d_ws;
    float* fsq      = ws;                           // 65536
    float* part_den = ws + 65536;                   // 4*256*8 = 8192
    float* proto_t  = part_den + 8192;              // 8192
    float* psq_part = proto_t + 8192;               // 256
    float* probs_ws = psq_part + 256;               // 524288
    float* part_num = probs_ws + 524288;            // 2097152 (~10.7 MB total)

    const dim3 pg(BB * NBLK), pb(512);
    const dim3 rg(256), rb(512);

    // seed pass + initial proto
    skm_pass<0><<<pg, pb, 0, stream>>>(feats, seed_w, seed_b, proto_t, psq_part,
                                       fsq, part_num, part_den, nullptr, nullptr);
    skm_reduce<false><<<rg, rb, 0, stream>>>(part_num, part_den, proto_t, psq_part,
                                             nullptr, probs_ws, probs_full);
    // cluster iterations 1,2
    skm_pass<1><<<pg, pb, 0, stream>>>(feats, seed_w, seed_b, proto_t, psq_part,
                                       fsq, part_num, part_den, nullptr, nullptr);
    skm_reduce<false><<<rg, rb, 0, stream>>>(part_num, part_den, proto_t, psq_part,
                                             nullptr, probs_ws, probs_full);
    skm_pass<1><<<pg, pb, 0, stream>>>(feats, seed_w, seed_b, proto_t, psq_part,
                                       fsq, part_num, part_den, nullptr, nullptr);
    skm_reduce<false><<<rg, rb, 0, stream>>>(part_num, part_den, proto_t, psq_part,
                                             nullptr, probs_ws, probs_full);
    // iteration 3: emit logits_map + probs(=assign)
    skm_pass<2><<<pg, pb, 0, stream>>>(feats, seed_w, seed_b, proto_t, psq_part,
                                       fsq, part_num, part_den, logits_out, probs_ws);
    // final reduce (proto -> d_out) + fused bilinear x4 upsample (512-wide)
    skm_reduce<true><<<dim3(256 + 4096), rb, 0, stream>>>(part_num, part_den, proto_t, psq_part,
                                                          proto_out, probs_ws, probs_full);
}